// Round 1
// baseline (413.978 us; speedup 1.0000x reference)
//
#include <hip/hip_runtime.h>
#include <hip/hip_bf16.h>
#include <math.h>

// softmask: [B=16, K=64, H=240, W=320] fp32. Per-slice unbiased variance over
// H*W = 76800 elements, sum the 1024 variances, sqrt -> scalar.
//
// Memory-bound: 314.6 MB read once. Accumulate in double to avoid fp32
// cancellation in (sumsq - sum^2/n).

#define HW_ELEMS 76800           // 240*320
#define HW_VEC4  (HW_ELEMS / 4)  // 19200 float4 per slice
#define BLOCK    256

__global__ __launch_bounds__(BLOCK) void slice_var_kernel(
    const float* __restrict__ in, float* __restrict__ vars) {
    const int slice = blockIdx.x;
    const float4* p = (const float4*)(in + (long long)slice * HW_ELEMS);

    double s = 0.0, sq = 0.0;
    // 19200 / 256 = 75 float4 per thread, coalesced: 256 lanes * 16B = 4KB/iter
    for (int i = threadIdx.x; i < HW_VEC4; i += BLOCK) {
        float4 v = p[i];
        s  += (double)v.x + (double)v.y + (double)v.z + (double)v.w;
        sq += (double)v.x * v.x + (double)v.y * v.y
            + (double)v.z * v.z + (double)v.w * v.w;
    }

    // wave64 shuffle reduction
    for (int off = 32; off > 0; off >>= 1) {
        s  += __shfl_down(s,  off, 64);
        sq += __shfl_down(sq, off, 64);
    }

    __shared__ double ss[BLOCK / 64], ssq[BLOCK / 64];
    const int wave = threadIdx.x >> 6;
    const int lane = threadIdx.x & 63;
    if (lane == 0) { ss[wave] = s; ssq[wave] = sq; }
    __syncthreads();

    if (threadIdx.x == 0) {
        double S = 0.0, SQ = 0.0;
        for (int w = 0; w < BLOCK / 64; ++w) { S += ss[w]; SQ += ssq[w]; }
        const double n = (double)HW_ELEMS;
        double var = (SQ - S * S / n) / (n - 1.0);
        vars[slice] = (float)var;
    }
}

__global__ __launch_bounds__(BLOCK) void finalize_kernel(
    const float* __restrict__ vars, float* __restrict__ out, int n_slices) {
    double s = 0.0;
    for (int i = threadIdx.x; i < n_slices; i += BLOCK) s += (double)vars[i];

    for (int off = 32; off > 0; off >>= 1) s += __shfl_down(s, off, 64);

    __shared__ double ss[BLOCK / 64];
    if ((threadIdx.x & 63) == 0) ss[threadIdx.x >> 6] = s;
    __syncthreads();

    if (threadIdx.x == 0) {
        double tot = 0.0;
        for (int w = 0; w < BLOCK / 64; ++w) tot += ss[w];
        out[0] = (float)sqrt(tot);
    }
}

extern "C" void kernel_launch(void* const* d_in, const int* in_sizes, int n_in,
                              void* d_out, int out_size, void* d_ws, size_t ws_size,
                              hipStream_t stream) {
    const float* softmask = (const float*)d_in[0];
    float* out = (float*)d_out;
    float* vars = (float*)d_ws;  // n_slices floats of scratch

    const int n_slices = in_sizes[0] / HW_ELEMS;  // 16*64 = 1024

    slice_var_kernel<<<n_slices, BLOCK, 0, stream>>>(softmask, vars);
    finalize_kernel<<<1, BLOCK, 0, stream>>>(vars, out, n_slices);
}

// Round 2
// 407.441 us; speedup vs baseline: 1.0160x; 1.0160x over previous
//
#include <hip/hip_runtime.h>
#include <hip/hip_bf16.h>
#include <math.h>

// softmask: [B=16, K=64, H=240, W=320] fp32. Per-slice unbiased variance over
// H*W = 76800, sum the 1024 variances, sqrt -> scalar.
//
// Stage 1: 5 chunks/slice, fp32 accumulation of sum(x-0.5) / sum((x-0.5)^2).
//   Shift-by-0.5 makes the later S^2/n cancellation benign, so no fp64 in the
//   hot loop. 15 float4/thread, compile-time trip count -> full unroll.
// Stage 2: 1 block, 1 thread/slice, combine chunk partials in double,
//   var = (Q - S^2/n)/(n-1), block-reduce, sqrt.

#define HW_ELEMS     76800            // 240*320
#define F4_PER_SLICE (HW_ELEMS / 4)   // 19200
#define CHUNKS       5
#define F4_PER_CHUNK (F4_PER_SLICE / CHUNKS)  // 3840
#define BLOCK        256
#define F4_PER_THR   (F4_PER_CHUNK / BLOCK)   // 15 exactly

__global__ __launch_bounds__(BLOCK) void chunk_partial_kernel(
    const float* __restrict__ in, float2* __restrict__ partials) {
    const long long chunk = blockIdx.x;  // slice*CHUNKS + c, contiguous memory
    const float4* __restrict__ p =
        (const float4*)in + chunk * F4_PER_CHUNK + threadIdx.x;

    float s = 0.0f, q = 0.0f;
#pragma unroll
    for (int j = 0; j < F4_PER_THR; ++j) {
        float4 v = p[j * BLOCK];
        float x = v.x - 0.5f, y = v.y - 0.5f, z = v.z - 0.5f, w = v.w - 0.5f;
        s += (x + y) + (z + w);
        q += x * x + y * y + z * z + w * w;
    }

    // wave64 shuffle reduction
    for (int off = 32; off > 0; off >>= 1) {
        s += __shfl_down(s, off, 64);
        q += __shfl_down(q, off, 64);
    }

    __shared__ float ss[BLOCK / 64], qq[BLOCK / 64];
    if ((threadIdx.x & 63) == 0) {
        ss[threadIdx.x >> 6] = s;
        qq[threadIdx.x >> 6] = q;
    }
    __syncthreads();

    if (threadIdx.x == 0) {
        float S = 0.0f, Q = 0.0f;
        for (int w = 0; w < BLOCK / 64; ++w) { S += ss[w]; Q += qq[w]; }
        partials[chunk] = make_float2(S, Q);
    }
}

// One thread per slice; n_slices <= 1024 assumed (it's exactly 1024 here).
__global__ __launch_bounds__(1024) void finalize_kernel(
    const float2* __restrict__ partials, float* __restrict__ out, int n_slices) {
    double var = 0.0;
    if ((int)threadIdx.x < n_slices) {
        double S = 0.0, Q = 0.0;
        const float2* p = partials + (long long)threadIdx.x * CHUNKS;
        for (int c = 0; c < CHUNKS; ++c) {
            float2 pq = p[c];
            S += (double)pq.x;
            Q += (double)pq.y;
        }
        const double n = (double)HW_ELEMS;
        var = (Q - S * S / n) / (n - 1.0);
    }

    for (int off = 32; off > 0; off >>= 1) var += __shfl_down(var, off, 64);

    __shared__ double sh[1024 / 64];
    if ((threadIdx.x & 63) == 0) sh[threadIdx.x >> 6] = var;
    __syncthreads();

    if (threadIdx.x == 0) {
        double tot = 0.0;
        for (int w = 0; w < 1024 / 64; ++w) tot += sh[w];
        out[0] = (float)sqrt(tot);
    }
}

extern "C" void kernel_launch(void* const* d_in, const int* in_sizes, int n_in,
                              void* d_out, int out_size, void* d_ws, size_t ws_size,
                              hipStream_t stream) {
    const float* softmask = (const float*)d_in[0];
    float* out = (float*)d_out;
    float2* partials = (float2*)d_ws;  // n_slices*CHUNKS float2

    const int n_slices = in_sizes[0] / HW_ELEMS;  // 1024

    chunk_partial_kernel<<<n_slices * CHUNKS, BLOCK, 0, stream>>>(softmask, partials);
    finalize_kernel<<<1, 1024, 0, stream>>>(partials, out, n_slices);
}